// Round 10
// baseline (145.269 us; speedup 1.0000x reference)
//
#include <hip/hip_runtime.h>
#include <math.h>

#define VOCAB 100000
#define DIM 128
#define BATCH 4096
#define CTX 20
#define NEGS 10
#define NTARG (CTX + CTX * NEGS)   // 220
#define NB 32                      // row buckets: 3125 rows = 1.6 MB slice
#define ROWS_PER_B 3125
#define CAP 20                     // recs per (bucket,b) cell; lambda=6.875, P(>20)~1e-5
#define SPILL_MAX 8192
#define SPILL_BLOCKS 8

// d_ws layout (bytes)
#define OFF_COUNTS   0u            // u8[NB*BATCH] = 131072
#define OFF_SPILLCNT 131072u       // u32 (+pad to 131200)
#define OFF_SPILL    131200u       // u32[SPILL_MAX] = 32768
#define OFF_RECORDS  163968u       // u16[NB*BATCH*CAP] = 5242880
#define OFF_IVEC     5406848u      // f32[BATCH*DIM] = 2097152 (16-aligned)
#define WS_NEEDED    7504000u

__device__ __forceinline__ float log_sigmoid_fast(float x) {
    float a = fabsf(x);
    return fminf(x, 0.0f) - __logf(1.0f + __expf(-a));
}

// ---- Kernel P: fused prep ----
// blocks [0,16):   per-example compact scatter into (bucket,b) cells, no atomics
// blocks [16,528): ivec[b] = W_i[i_words[b]] dense stage
__global__ __launch_bounds__(256) void prep_kernel(
    const int* __restrict__ i_words, const int* __restrict__ o_words,
    const int* __restrict__ n_words, const float4* __restrict__ W_i4,
    float4* __restrict__ ivec4, unsigned short* __restrict__ records,
    unsigned char* __restrict__ counts, unsigned* __restrict__ spillcnt,
    unsigned* __restrict__ spill)
{
    if (blockIdx.x >= 16) {
        int tid = (blockIdx.x - 16) * 256 + threadIdx.x;   // 131072 = BATCH*32
        int b = tid >> 5, q = tid & 31;
        ivec4[tid] = W_i4[i_words[b] * 32 + q];
        return;
    }
    __shared__ unsigned lcnt[NB * 256];   // [bucket][tid] private counters, 32 KB
    const int tid = threadIdx.x;
    const int b   = blockIdx.x * 256 + tid;    // 0..4095
    #pragma unroll
    for (int k = 0; k < NB; ++k) lcnt[k * 256 + tid] = 0;

    #pragma unroll 4
    for (int j = 0; j < NTARG; ++j) {
        int idx; unsigned negbit;
        if (j < CTX) { idx = o_words[j * BATCH + b];              negbit = 0u; }      // coalesced
        else         { idx = n_words[b * (CTX * NEGS) + (j - CTX)]; negbit = 0x1000u; } // L1-sequential
        unsigned bucket = (unsigned)idx / ROWS_PER_B;              // magic-mul
        unsigned rl     = (unsigned)idx - bucket * ROWS_PER_B;     // 0..3124 (12 bits)
        unsigned c = lcnt[bucket * 256 + tid];
        lcnt[bucket * 256 + tid] = c + 1u;
        if (c < CAP) {
            records[((bucket << 12) + (unsigned)b) * CAP + c] = (unsigned short)(rl | negbit);
        } else {
            unsigned s = atomicAdd(spillcnt, 1u);                  // ~never
            if (s < SPILL_MAX) spill[s] = ((unsigned)idx << 13) | ((unsigned)b << 1) | (negbit ? 1u : 0u);
        }
    }
    #pragma unroll
    for (int k = 0; k < NB; ++k) {
        unsigned c = lcnt[k * 256 + tid];
        counts[(k << 12) + (unsigned)b] = (unsigned char)(c < CAP ? c : CAP);
    }
}

// ---- Kernel C: one 16-lane group per (bucket,b) cell; ivec loaded once;
//      rows batch-prefetched 8-deep; XCD-affine in-phase bucket walk ----
__global__ __launch_bounds__(256) void bucket_loss_kernel(
    const float* __restrict__ W_os, const float* __restrict__ ivec,
    const unsigned short* __restrict__ records, const unsigned char* __restrict__ counts,
    const unsigned* __restrict__ spillcnt, const unsigned* __restrict__ spill,
    float* __restrict__ out)
{
    const int t    = threadIdx.x & 15;
    const int grp  = threadIdx.x >> 4;
    const int lane = threadIdx.x & 63;
    const int wave = threadIdx.x >> 6;
    const unsigned tb = (unsigned)t << 5;          // byte offset within 512B row
    const unsigned* rec32 = (const unsigned*)records;

    float acc = 0.0f;
    const int lid = blockIdx.x;

    if (lid < 2048) {
        const int xcd = lid & 7;                   // blockIdx%8 -> XCD heuristic
        const int s   = lid >> 3;                  // 0..255
        const unsigned bcell = (unsigned)(s * 16 + grp);   // example b, 0..4095

        const char* vp = (const char*)ivec + ((bcell << 9) + tb);
        const float4 v0 = *(const float4*)vp;      // ivec loaded ONCE per group
        const float4 v1 = *(const float4*)(vp + 16);

        for (int bk = 0; bk < NB / 8; ++bk) {      // 4 buckets per XCD, in phase
            const unsigned bucket = (unsigned)(xcd * (NB / 8) + bk);
            const unsigned cell   = (bucket << 12) + bcell;
            const unsigned cnt    = counts[cell];
            unsigned w = 0;
            if (t < 10) w = rec32[cell * 10u + (unsigned)t];   // 20 u16 recs = 10 u32

            for (unsigned base = 0; base < cnt; base += 8) {
                unsigned recs[8]; float4 r0[8], r1[8];
                #pragma unroll
                for (int i = 0; i < 8; ++i) {      // broadcast recs + issue 16 loads
                    unsigned ji = base + (unsigned)i;
                    int src = (grp << 4) + (int)(ji >> 1);
                    unsigned wv  = __shfl(w, src, 64);
                    unsigned rec = (i & 1) ? (wv >> 16) : (wv & 0xffffu);
                    recs[i] = rec;
                    unsigned rowg = (ji < cnt) ? (bucket * ROWS_PER_B + (rec & 0xfffu)) : 0u;
                    const char* rp = (const char*)W_os + ((rowg << 9) + tb);
                    r0[i] = *(const float4*)rp;
                    r1[i] = *(const float4*)(rp + 16);
                }
                #pragma unroll
                for (int i = 0; i < 8; ++i) {      // reduce + loss
                    unsigned ji = base + (unsigned)i;
                    float pd = r0[i].x*v0.x + r0[i].y*v0.y + r0[i].z*v0.z + r0[i].w*v0.w
                             + r1[i].x*v1.x + r1[i].y*v1.y + r1[i].z*v1.z + r1[i].w*v1.w;
                    pd += __shfl_xor(pd, 1);
                    pd += __shfl_xor(pd, 2);
                    pd += __shfl_xor(pd, 4);
                    pd += __shfl_xor(pd, 8);
                    float term = (recs[i] & 0x1000u)
                               ? (1.0f / NEGS) * log_sigmoid_fast(-pd)
                               : (1.0f / CTX)  * log_sigmoid_fast(pd);
                    if (t == 0 && ji < cnt) acc += term;
                }
            }
        }
    } else {
        // spill groups (exactness; expected ~0-5 entries)
        int sg = (lid - 2048) * 16 + grp;          // 0..127
        unsigned ns = *spillcnt; if (ns > SPILL_MAX) ns = SPILL_MAX;
        for (unsigned s = sg; s < ns; s += 16 * SPILL_BLOCKS) {
            unsigned e = spill[s];
            unsigned row = e >> 13, bb = (e >> 1) & 4095u;
            const char* rp = (const char*)W_os + ((row << 9) + tb);
            float4 r0 = *(const float4*)rp, r1 = *(const float4*)(rp + 16);
            const char* vp2 = (const char*)ivec + ((bb << 9) + tb);
            float4 v0 = *(const float4*)vp2, v1 = *(const float4*)(vp2 + 16);
            float pd = r0.x*v0.x + r0.y*v0.y + r0.z*v0.z + r0.w*v0.w
                     + r1.x*v1.x + r1.y*v1.y + r1.z*v1.z + r1.w*v1.w;
            pd += __shfl_xor(pd, 1);
            pd += __shfl_xor(pd, 2);
            pd += __shfl_xor(pd, 4);
            pd += __shfl_xor(pd, 8);
            float term = (e & 1u) ? (1.0f / NEGS) * log_sigmoid_fast(-pd)
                                  : (1.0f / CTX)  * log_sigmoid_fast(pd);
            if (t == 0) acc += term;
        }
    }

    acc += __shfl_xor(acc, 16);
    acc += __shfl_xor(acc, 32);
    __shared__ float wsum[4];
    if (lane == 0) wsum[wave] = acc;
    __syncthreads();
    if (threadIdx.x == 0) {
        float sum = wsum[0] + wsum[1] + wsum[2] + wsum[3];
        if (sum != 0.0f) atomicAdd(out, -sum);
    }
}

// ---- Fallback (round-5 direct kernel) if ws too small ----
__global__ __launch_bounds__(256) void sgns_loss_direct(
    const int* __restrict__ i_words, const int* __restrict__ o_words,
    const int* __restrict__ n_words, const float* __restrict__ W_i,
    const float* __restrict__ W_os, float* __restrict__ out)
{
    const int lane = threadIdx.x & 63;
    const int wave = threadIdx.x >> 6;
    const int w    = blockIdx.x * 4 + wave;
    const int b    = w >> 1;
    const int h    = w & 1;
    const int sub = lane >> 4;
    const int t   = lane & 15;
    const int j_begin = h ? 112 : 0;
    const int j_end   = h ? NTARG : 112;
    float acc = 0.0f;
    const int ic = i_words[b];
    const char* ibase = (const char*)W_i + (((unsigned)ic << 9) + ((unsigned)t << 5));
    float4 i0 = *(const float4*)(ibase);
    float4 i1 = *(const float4*)(ibase + 16);
    #pragma unroll 4
    for (int j0 = j_begin; j0 < j_end; j0 += 4) {
        int jj = j0 + sub;
        int idx; float sgn, wgt;
        if (jj < CTX) { idx = o_words[jj * BATCH + b]; sgn = 1.0f; wgt = 1.0f / CTX; }
        else { idx = n_words[b * (CTX * NEGS) + (jj - CTX)]; sgn = -1.0f; wgt = 1.0f / NEGS; }
        const char* obase = (const char*)W_os + (((unsigned)idx << 9) + ((unsigned)t << 5));
        float4 o0 = *(const float4*)(obase);
        float4 o1 = *(const float4*)(obase + 16);
        float p = i0.x*o0.x + i0.y*o0.y + i0.z*o0.z + i0.w*o0.w
                + i1.x*o1.x + i1.y*o1.y + i1.z*o1.z + i1.w*o1.w;
        p += __shfl_xor(p, 1); p += __shfl_xor(p, 2);
        p += __shfl_xor(p, 4); p += __shfl_xor(p, 8);
        acc += (t == 0) ? wgt * log_sigmoid_fast(sgn * p) : 0.0f;
    }
    acc += __shfl_xor(acc, 16);
    acc += __shfl_xor(acc, 32);
    __shared__ float ws[4];
    if (lane == 0) ws[wave] = acc;
    __syncthreads();
    if (threadIdx.x == 0) atomicAdd(out, -(ws[0] + ws[1] + ws[2] + ws[3]));
}

extern "C" void kernel_launch(void* const* d_in, const int* in_sizes, int n_in,
                              void* d_out, int out_size, void* d_ws, size_t ws_size,
                              hipStream_t stream) {
    const int*   i_words = (const int*)d_in[0];
    const int*   o_words = (const int*)d_in[1];
    const int*   n_words = (const int*)d_in[2];
    const float* W_i     = (const float*)d_in[3];
    const float* W_os    = (const float*)d_in[4];
    float* out = (float*)d_out;

    hipMemsetAsync(out, 0, sizeof(float), stream);

    if (ws_size < (size_t)WS_NEEDED) {
        sgns_loss_direct<<<2048, 256, 0, stream>>>(i_words, o_words, n_words, W_i, W_os, out);
        return;
    }

    char* ws = (char*)d_ws;
    unsigned char*  counts   = (unsigned char*)(ws + OFF_COUNTS);
    unsigned*       spillcnt = (unsigned*)(ws + OFF_SPILLCNT);
    unsigned*       spill    = (unsigned*)(ws + OFF_SPILL);
    unsigned short* records  = (unsigned short*)(ws + OFF_RECORDS);
    float*          ivec     = (float*)(ws + OFF_IVEC);

    // zero counts + spillcnt (harness does not re-zero ws between replays)
    hipMemsetAsync(ws, 0, 131200, stream);

    prep_kernel<<<528, 256, 0, stream>>>(i_words, o_words, n_words,
                                         (const float4*)W_i, (float4*)ivec,
                                         records, counts, spillcnt, spill);
    bucket_loss_kernel<<<2048 + SPILL_BLOCKS, 256, 0, stream>>>(
        W_os, ivec, records, counts, spillcnt, spill, out);
}

// Round 11
// 73.076 us; speedup vs baseline: 1.9879x; 1.9879x over previous
//
#include <hip/hip_runtime.h>
#include <math.h>

#define VOCAB 100000
#define DIM 128
#define BATCH 4096
#define CTX 20
#define NEGS 10
#define NTARG (CTX + CTX * NEGS)   // 220
#define NB 32                      // row buckets: 3125 rows = 1.6 MB slice
#define ROWS_PER_B 3125
#define CAP 20                     // recs per (bucket,b) cell; lambda=6.875
#define SPILL_MAX 8192
#define SPILL_BLOCKS 8

// d_ws layout (bytes)
#define OFF_COUNTS   0u            // u8[NB*BATCH] = 131072
#define OFF_SPILLCNT 131072u       // u32 (+pad to 131200)
#define OFF_SPILL    131200u       // u32[SPILL_MAX] = 32768
#define OFF_RECORDS  163968u       // u16[NB*BATCH*CAP] = 5242880
#define OFF_IVEC     5406848u      // f32[BATCH*DIM] = 2097152 (16-aligned)
#define WS_NEEDED    7504000u

__device__ __forceinline__ float log_sigmoid_fast(float x) {
    float a = fabsf(x);
    return fminf(x, 0.0f) - __logf(1.0f + __expf(-a));
}

// ---- Kernel P: fused prep ----
// blocks [0,256):   scatter — 16 examples/block, 16 threads/example, LDS-atomic cell counters
// blocks [256,768): ivec[b] = W_i[i_words[b]] dense stage
__global__ __launch_bounds__(256) void prep_kernel(
    const int* __restrict__ i_words, const int* __restrict__ o_words,
    const int* __restrict__ n_words, const float4* __restrict__ W_i4,
    float4* __restrict__ ivec4, unsigned short* __restrict__ records,
    unsigned char* __restrict__ counts, unsigned* __restrict__ spillcnt,
    unsigned* __restrict__ spill)
{
    if (blockIdx.x >= 256) {
        int tid = (blockIdx.x - 256) * 256 + threadIdx.x;   // 131072 = BATCH*32
        int b = tid >> 5, q = tid & 31;
        ivec4[tid] = W_i4[i_words[b] * 32 + q];
        return;
    }
    const int exl = threadIdx.x >> 4;          // 0..15: example within block
    const int t   = threadIdx.x & 15;
    const int b   = blockIdx.x * 16 + exl;     // 0..4095

    __shared__ unsigned lcnt[NB * 16];         // [bucket*16 + exl], 2 KB
    for (int k = threadIdx.x; k < NB * 16; k += 256) lcnt[k] = 0;
    __syncthreads();

    for (int j = t; j < NTARG; j += 16) {      // 14 iters; negatives coalesce per line
        int idx; unsigned negbit;
        if (j < CTX) { idx = o_words[j * BATCH + b];                negbit = 0u; }
        else         { idx = n_words[b * (CTX * NEGS) + (j - CTX)]; negbit = 0x1000u; }
        unsigned bucket = (unsigned)idx / ROWS_PER_B;               // magic-mul
        unsigned rl     = (unsigned)idx - bucket * ROWS_PER_B;      // 0..3124
        unsigned slot = atomicAdd(&lcnt[bucket * 16 + (unsigned)exl], 1u);
        if (slot < CAP) {
            records[((bucket << 12) + (unsigned)b) * CAP + slot] = (unsigned short)(rl | negbit);
        } else {
            unsigned s = atomicAdd(spillcnt, 1u);                   // ~1 per run
            if (s < SPILL_MAX) spill[s] = ((unsigned)idx << 13) | ((unsigned)b << 1) | (negbit ? 1u : 0u);
        }
    }
    __syncthreads();
    for (int k = threadIdx.x; k < NB * 16; k += 256) {
        unsigned c = lcnt[k];
        unsigned bucket = (unsigned)k >> 4, e2 = (unsigned)k & 15u;
        counts[(bucket << 12) + (unsigned)blockIdx.x * 16 + e2] = (unsigned char)(c < CAP ? c : CAP);
    }
}

// ---- Kernel C: one 16-lane group per (bucket,b) cell; ivec loaded once;
//      rows batch-prefetched 8-deep; XCD-affine in-phase bucket walk ----
__global__ __launch_bounds__(256) void bucket_loss_kernel(
    const float* __restrict__ W_os, const float* __restrict__ ivec,
    const unsigned short* __restrict__ records, const unsigned char* __restrict__ counts,
    const unsigned* __restrict__ spillcnt, const unsigned* __restrict__ spill,
    float* __restrict__ out)
{
    const int t    = threadIdx.x & 15;
    const int grp  = threadIdx.x >> 4;
    const int lane = threadIdx.x & 63;
    const int wave = threadIdx.x >> 6;
    const unsigned tb = (unsigned)t << 5;          // byte offset within 512B row
    const unsigned* rec32 = (const unsigned*)records;

    float acc = 0.0f;
    const int lid = blockIdx.x;

    if (lid < 2048) {
        const int xcd = lid & 7;                   // blockIdx%8 -> XCD heuristic
        const int s   = lid >> 3;                  // 0..255
        const unsigned bcell = (unsigned)(s * 16 + grp);   // example b, 0..4095

        const char* vp = (const char*)ivec + ((bcell << 9) + tb);
        const float4 v0 = *(const float4*)vp;      // ivec loaded ONCE per group
        const float4 v1 = *(const float4*)(vp + 16);

        for (int bk = 0; bk < NB / 8; ++bk) {      // 4 buckets per XCD, in phase
            const unsigned bucket = (unsigned)(xcd * (NB / 8) + bk);
            const unsigned cell   = (bucket << 12) + bcell;
            const unsigned cnt    = counts[cell];
            unsigned w = 0;
            if (t < 10) w = rec32[cell * 10u + (unsigned)t];   // 20 u16 recs = 10 u32

            for (unsigned base = 0; base < cnt; base += 8) {
                unsigned recs[8]; float4 r0[8], r1[8];
                #pragma unroll
                for (int i = 0; i < 8; ++i) {      // broadcast recs + issue 16 loads
                    unsigned ji = base + (unsigned)i;
                    int src = (grp << 4) + (int)(ji >> 1);
                    unsigned wv  = __shfl(w, src, 64);
                    unsigned rec = (i & 1) ? (wv >> 16) : (wv & 0xffffu);
                    recs[i] = rec;
                    unsigned rowg = (ji < cnt) ? (bucket * ROWS_PER_B + (rec & 0xfffu)) : 0u;
                    const char* rp = (const char*)W_os + ((rowg << 9) + tb);
                    r0[i] = *(const float4*)rp;
                    r1[i] = *(const float4*)(rp + 16);
                }
                #pragma unroll
                for (int i = 0; i < 8; ++i) {      // reduce + loss
                    unsigned ji = base + (unsigned)i;
                    float pd = r0[i].x*v0.x + r0[i].y*v0.y + r0[i].z*v0.z + r0[i].w*v0.w
                             + r1[i].x*v1.x + r1[i].y*v1.y + r1[i].z*v1.z + r1[i].w*v1.w;
                    pd += __shfl_xor(pd, 1);
                    pd += __shfl_xor(pd, 2);
                    pd += __shfl_xor(pd, 4);
                    pd += __shfl_xor(pd, 8);
                    float term = (recs[i] & 0x1000u)
                               ? (1.0f / NEGS) * log_sigmoid_fast(-pd)
                               : (1.0f / CTX)  * log_sigmoid_fast(pd);
                    if (t == 0 && ji < cnt) acc += term;
                }
            }
        }
    } else {
        // spill groups (exactness; expected ~0-5 entries)
        int sg = (lid - 2048) * 16 + grp;          // 0..127
        unsigned ns = *spillcnt; if (ns > SPILL_MAX) ns = SPILL_MAX;
        for (unsigned s = sg; s < ns; s += 16 * SPILL_BLOCKS) {
            unsigned e = spill[s];
            unsigned row = e >> 13, bb = (e >> 1) & 4095u;
            const char* rp = (const char*)W_os + ((row << 9) + tb);
            float4 r0 = *(const float4*)rp, r1 = *(const float4*)(rp + 16);
            const char* vp2 = (const char*)ivec + ((bb << 9) + tb);
            float4 v0 = *(const float4*)vp2, v1 = *(const float4*)(vp2 + 16);
            float pd = r0.x*v0.x + r0.y*v0.y + r0.z*v0.z + r0.w*v0.w
                     + r1.x*v1.x + r1.y*v1.y + r1.z*v1.z + r1.w*v1.w;
            pd += __shfl_xor(pd, 1);
            pd += __shfl_xor(pd, 2);
            pd += __shfl_xor(pd, 4);
            pd += __shfl_xor(pd, 8);
            float term = (e & 1u) ? (1.0f / NEGS) * log_sigmoid_fast(-pd)
                                  : (1.0f / CTX)  * log_sigmoid_fast(pd);
            if (t == 0) acc += term;
        }
    }

    acc += __shfl_xor(acc, 16);
    acc += __shfl_xor(acc, 32);
    __shared__ float wsum[4];
    if (lane == 0) wsum[wave] = acc;
    __syncthreads();
    if (threadIdx.x == 0) {
        float sum = wsum[0] + wsum[1] + wsum[2] + wsum[3];
        if (sum != 0.0f) atomicAdd(out, -sum);
    }
}

// ---- Fallback (round-5 direct kernel) if ws too small ----
__global__ __launch_bounds__(256) void sgns_loss_direct(
    const int* __restrict__ i_words, const int* __restrict__ o_words,
    const int* __restrict__ n_words, const float* __restrict__ W_i,
    const float* __restrict__ W_os, float* __restrict__ out)
{
    const int lane = threadIdx.x & 63;
    const int wave = threadIdx.x >> 6;
    const int w    = blockIdx.x * 4 + wave;
    const int b    = w >> 1;
    const int h    = w & 1;
    const int sub = lane >> 4;
    const int t   = lane & 15;
    const int j_begin = h ? 112 : 0;
    const int j_end   = h ? NTARG : 112;
    float acc = 0.0f;
    const int ic = i_words[b];
    const char* ibase = (const char*)W_i + (((unsigned)ic << 9) + ((unsigned)t << 5));
    float4 i0 = *(const float4*)(ibase);
    float4 i1 = *(const float4*)(ibase + 16);
    #pragma unroll 4
    for (int j0 = j_begin; j0 < j_end; j0 += 4) {
        int jj = j0 + sub;
        int idx; float sgn, wgt;
        if (jj < CTX) { idx = o_words[jj * BATCH + b]; sgn = 1.0f; wgt = 1.0f / CTX; }
        else { idx = n_words[b * (CTX * NEGS) + (jj - CTX)]; sgn = -1.0f; wgt = 1.0f / NEGS; }
        const char* obase = (const char*)W_os + (((unsigned)idx << 9) + ((unsigned)t << 5));
        float4 o0 = *(const float4*)(obase);
        float4 o1 = *(const float4*)(obase + 16);
        float p = i0.x*o0.x + i0.y*o0.y + i0.z*o0.z + i0.w*o0.w
                + i1.x*o1.x + i1.y*o1.y + i1.z*o1.z + i1.w*o1.w;
        p += __shfl_xor(p, 1); p += __shfl_xor(p, 2);
        p += __shfl_xor(p, 4); p += __shfl_xor(p, 8);
        acc += (t == 0) ? wgt * log_sigmoid_fast(sgn * p) : 0.0f;
    }
    acc += __shfl_xor(acc, 16);
    acc += __shfl_xor(acc, 32);
    __shared__ float ws[4];
    if (lane == 0) ws[wave] = acc;
    __syncthreads();
    if (threadIdx.x == 0) atomicAdd(out, -(ws[0] + ws[1] + ws[2] + ws[3]));
}

extern "C" void kernel_launch(void* const* d_in, const int* in_sizes, int n_in,
                              void* d_out, int out_size, void* d_ws, size_t ws_size,
                              hipStream_t stream) {
    const int*   i_words = (const int*)d_in[0];
    const int*   o_words = (const int*)d_in[1];
    const int*   n_words = (const int*)d_in[2];
    const float* W_i     = (const float*)d_in[3];
    const float* W_os    = (const float*)d_in[4];
    float* out = (float*)d_out;

    hipMemsetAsync(out, 0, sizeof(float), stream);

    if (ws_size < (size_t)WS_NEEDED) {
        sgns_loss_direct<<<2048, 256, 0, stream>>>(i_words, o_words, n_words, W_i, W_os, out);
        return;
    }

    char* ws = (char*)d_ws;
    unsigned char*  counts   = (unsigned char*)(ws + OFF_COUNTS);
    unsigned*       spillcnt = (unsigned*)(ws + OFF_SPILLCNT);
    unsigned*       spill    = (unsigned*)(ws + OFF_SPILL);
    unsigned short* records  = (unsigned short*)(ws + OFF_RECORDS);
    float*          ivec     = (float*)(ws + OFF_IVEC);

    // counts cells are all overwritten by prep; only spillcnt needs zeroing
    hipMemsetAsync(spillcnt, 0, sizeof(unsigned), stream);

    prep_kernel<<<768, 256, 0, stream>>>(i_words, o_words, n_words,
                                         (const float4*)W_i, (float4*)ivec,
                                         records, counts, spillcnt, spill);
    bucket_loss_kernel<<<2048 + SPILL_BLOCKS, 256, 0, stream>>>(
        W_os, ivec, records, counts, spillcnt, spill, out);
}